// Round 4
// baseline (155.945 us; speedup 1.0000x reference)
//
#include <hip/hip_runtime.h>

// y[n,c,h,w] = x[n,c,h,w] * w[c] + b[c]
// x: (32, 64, 224, 224) fp32. One workgroup per (n,c) plane.
// Plane = 50176 floats = 12544 float4 = 49 * 256 = 3*16*256 + 256.
// 3 batches of 16 float4 in flight (256 B/lane), then FMA+store; NT hints
// (pure streaming, zero reuse). Tail = 1 iteration.

typedef float f32x4 __attribute__((ext_vector_type(4)));

__global__ __launch_bounds__(256) void scale_kernel(
    const f32x4* __restrict__ x,
    const float* __restrict__ w,
    const float* __restrict__ b,
    f32x4*       __restrict__ y) {
    const int plane = blockIdx.x;          // 0..2047  (= n*64 + c)
    const int c = plane & 63;
    const float wc = w[c];
    const float bc = b[c];

    const long long base = (long long)plane * 12544;
    const f32x4* __restrict__ xp = x + base;
    f32x4*       __restrict__ yp = y + base;
    const int tid = threadIdx.x;

    for (int bi = 0; bi < 3; ++bi) {
        const int o = bi * 4096 + tid;     // 16*256 = 4096 vec per batch
        f32x4 v[16];
        #pragma unroll
        for (int j = 0; j < 16; ++j)
            v[j] = __builtin_nontemporal_load(&xp[o + j * 256]);
        #pragma unroll
        for (int j = 0; j < 16; ++j) {
            f32x4 t = v[j];
            t.x = fmaf(t.x, wc, bc);
            t.y = fmaf(t.y, wc, bc);
            t.z = fmaf(t.z, wc, bc);
            t.w = fmaf(t.w, wc, bc);
            __builtin_nontemporal_store(t, &yp[o + j * 256]);
        }
    }
    {   // tail iteration: 49th vec per thread
        const int o = 12288 + tid;
        f32x4 t = __builtin_nontemporal_load(&xp[o]);
        t.x = fmaf(t.x, wc, bc);
        t.y = fmaf(t.y, wc, bc);
        t.z = fmaf(t.z, wc, bc);
        t.w = fmaf(t.w, wc, bc);
        __builtin_nontemporal_store(t, &yp[o]);
    }
}

extern "C" void kernel_launch(void* const* d_in, const int* in_sizes, int n_in,
                              void* d_out, int out_size, void* d_ws, size_t ws_size,
                              hipStream_t stream) {
    const float* x = (const float*)d_in[0];
    const float* w = (const float*)d_in[1];
    const float* b = (const float*)d_in[2];
    float* y = (float*)d_out;

    const int planes = 32 * 64;  // 2048 workgroups
    scale_kernel<<<planes, 256, 0, stream>>>(
        (const f32x4*)x, w, b, (f32x4*)y);
}